// Round 3
// baseline (360.417 us; speedup 1.0000x reference)
//
#include <hip/hip_runtime.h>
#include <math.h>

#define N_NODES 10000
#define N_EDGES 50000
#define IN_F    1433
#define OUT_F   256
#define GK      1440          // padded K: multiple of 32, rows 16B-aligned
#define NCHUNK  180           // GK/8
#define GM2     10112         // 79*128: agg rows padded to GEMM M tiles

typedef __bf16 bf16x8 __attribute__((ext_vector_type(8)));
typedef float  f32x4  __attribute__((ext_vector_type(4)));

typedef __attribute__((address_space(3))) unsigned int lds_u32;
typedef __attribute__((address_space(1))) unsigned int glb_u32;

__device__ __forceinline__ void stage16(const void* g, void* l) {
    __builtin_amdgcn_global_load_lds((glb_u32*)g, (lds_u32*)l, 16, 0, 0);
}

// ---------------- phase A: ONE dispatch ----------------
// block 0          : full CSR build (LDS histogram -> LDS scan -> LDS-cursor fill)
// blocks 1..2500   : fp32->bf16 convert of X (4 rows/block, window-select)
// blocks 2501..3940: W^T prep (bf16, zero-padded K)
//
// CSR in one block: counts[10000] = 40 KB LDS (every block pays the 40 KB ->
// 4 blocks/CU, 16 waves/CU -- fine for the BW-bound conv path). Edges are
// int32 pairs [dst,src] (JAX x64 disabled: int64 request lowers to int32).
//
// conv window-select: wave w owns row r = (blk-1)*4 + w; row start mod 4 == r&3
// == d (1433 % 4 == 1) -> uniform branch picks dwords [d..d+7] from 3 aligned
// float4 loads, ALL hoisted up front (one latency per row, not three).
// Loads clamp chunk to 178; chunk 178's 12-float window ends at col 1432
// (worst: row 9999, d=3 lands exactly on the last element 14,329,999).
// Chunk 179's single valid float (col 1432) sits at q[8+d] of that window.

#define PREP_W      (OUT_F * GK)         // 368640 = 1440 blocks * 256
#define CONV_BLKS   (N_NODES / 4)        // 2500
#define PREP_BLKS   (PREP_W / 256)       // 1440
#define PHASEA_BLKS (1 + CONV_BLKS + PREP_BLKS)

__global__ void __launch_bounds__(256) k_phaseA(const float* __restrict__ X,
                                                __bf16* __restrict__ Xbf,
                                                const float* __restrict__ W,
                                                __bf16* __restrict__ BT,
                                                const int* __restrict__ edges,
                                                int* __restrict__ offsets,
                                                int* __restrict__ edge_src) {
    __shared__ int cnt[N_NODES];         // 40 KB: counts -> cursor
    __shared__ int wtot[4];
    const int t = threadIdx.x;
    const int b = blockIdx.x;

    if (b == 0) {
        // ---- CSR build, entirely block-local ----
        for (int i = t; i < N_NODES; i += 256) cnt[i] = 0;
        __syncthreads();
        // histogram (LDS atomics)
        for (int e = t; e < N_EDGES; e += 256) {
            int dst = edges[2 * e];
            int src = edges[2 * e + 1];
            if ((unsigned)src < N_NODES) atomicAdd(&cnt[dst], 1);
        }
        __syncthreads();
        // chunked exclusive scan: thread t owns [t*40, t*40+40)
        const int lane = t & 63, wid = t >> 6;
        const int base = t * 40;
        int lsum = 0;
        for (int j = 0; j < 40; ++j) {
            int idx = base + j;
            if (idx < N_NODES) lsum += cnt[idx];
        }
        int s = lsum;
#pragma unroll
        for (int off = 1; off < 64; off <<= 1) {
            int u = __shfl_up(s, off, 64);
            if (lane >= off) s += u;
        }
        if (lane == 63) wtot[wid] = s;
        __syncthreads();
        int carry = 0;
        for (int w2 = 0; w2 < wid; ++w2) carry += wtot[w2];
        int run = carry + s - lsum;      // exclusive prefix of this chunk
        for (int j = 0; j < 40; ++j) {
            int idx = base + j;
            if (idx < N_NODES) {
                int v = cnt[idx];
                cnt[idx] = run;          // becomes the fill cursor
                offsets[idx] = run;
                run += v;
            }
        }
        if (t == 255) offsets[N_NODES] = run;   // chunk empty -> run == grand total
        __syncthreads();
        // fill (LDS cursor atomics)
        for (int e = t; e < N_EDGES; e += 256) {
            int dst = edges[2 * e];
            int src = edges[2 * e + 1];
            if ((unsigned)src < N_NODES) {
                int pos = atomicAdd(&cnt[dst], 1);
                edge_src[pos] = src;
            }
        }
        return;
    }

    if (b <= CONV_BLKS) {
        // ---- conv: fp32 -> bf16, ILP-hoisted window-select ----
        const int w = t >> 6, lane = t & 63;
        const int r = (b - 1) * 4 + w;               // 0..9999
        const size_t rowf = (size_t)r * IN_F;
        __bf16* orow = Xbf + (size_t)r * GK;
        const int d = r & 3;

        f32x4 A[3][3];
#pragma unroll
        for (int s2 = 0; s2 < 3; ++s2) {
            int k = lane + s2 * 64;
            int kc = (k > 178) ? 178 : k;            // clamped: always in-bounds
            size_t q0 = (rowf + (size_t)kc * 8) >> 2;
            A[s2][0] = ((const f32x4*)X)[q0];
            A[s2][1] = ((const f32x4*)X)[q0 + 1];
            A[s2][2] = ((const f32x4*)X)[q0 + 2];
        }

#pragma unroll
        for (int s2 = 0; s2 < 3; ++s2) {
            int k = lane + s2 * 64;
            float q[12];
            *(f32x4*)&q[0] = A[s2][0];
            *(f32x4*)&q[4] = A[s2][1];
            *(f32x4*)&q[8] = A[s2][2];
            if (k < 179) {
                bf16x8 v;
                switch (d) {                          // wave-uniform
                case 0:
#pragma unroll
                    for (int j = 0; j < 8; ++j) v[j] = (__bf16)q[0 + j];
                    break;
                case 1:
#pragma unroll
                    for (int j = 0; j < 8; ++j) v[j] = (__bf16)q[1 + j];
                    break;
                case 2:
#pragma unroll
                    for (int j = 0; j < 8; ++j) v[j] = (__bf16)q[2 + j];
                    break;
                default:
#pragma unroll
                    for (int j = 0; j < 8; ++j) v[j] = (__bf16)q[3 + j];
                    break;
                }
                *(bf16x8*)(orow + k * 8) = v;
            } else if (k == 179) {
                bf16x8 v;
                v[0] = (__bf16)q[8 + d];              // float col 1432
#pragma unroll
                for (int j = 1; j < 8; ++j) v[j] = (__bf16)0.0f;
                *(bf16x8*)(orow + 1432) = v;
            }
        }
        return;
    }

    // ---- prep: W^T (bf16, zero-padded K) ----
    {
        int i = (b - 1 - CONV_BLKS) * 256 + t;        // 0..368639
        int n = i / GK, k = i % GK;
        BT[i] = (__bf16)((k < IN_F) ? W[(size_t)k * OUT_F + n] : 0.0f);
    }
}

// ---------------- aggregate: barrier-free, bf16x8 gathers + fp32 noise init ---
// agg[i] = noise[i] + sum_{src in N(i)} X[src];  rnorm[i] = 1/max(||agg||,1e-12)
// noise is read DIRECTLY as fp32 with the same window-select (d = node&3 is
// block-uniform); its 3 loads are issued before the gather loop so they fly
// under it. grid = GM2: blocks >= N_NODES just zero their pad row.

__global__ void __launch_bounds__(192) k_agg(const __bf16* __restrict__ Xbf,
                                             const float* __restrict__ noise,
                                             const int* __restrict__ offsets,
                                             const int* __restrict__ edge_src,
                                             __bf16* __restrict__ aggbf,
                                             float* __restrict__ rnorm) {
    __shared__ float red[3];
    const int node = blockIdx.x;
    const int t = threadIdx.x;
    const bool active = (t < NCHUNK);
    const size_t co = (size_t)t * 8;

    if (node >= N_NODES) {          // pad rows for the GEMM M-tiling
        if (active) {
            bf16x8 z;
#pragma unroll
            for (int j = 0; j < 8; ++j) z[j] = (__bf16)0.0f;
            *(bf16x8*)(aggbf + (size_t)node * GK + co) = z;
        }
        return;
    }

    // issue noise window loads early (fp32, clamped chunk <= 178: in-bounds,
    // see k_phaseA conv comment)
    const size_t nrowf = (size_t)node * IN_F;
    const int d = node & 3;
    f32x4 na, nb, nc;
    if (active) {
        int kc = (t > 178) ? 178 : t;
        size_t q0 = (nrowf + (size_t)kc * 8) >> 2;
        na = ((const f32x4*)noise)[q0];
        nb = ((const f32x4*)noise)[q0 + 1];
        nc = ((const f32x4*)noise)[q0 + 2];
    }

    const int beg = offsets[node], end = offsets[node + 1];

    float acc[8] = {0.f, 0.f, 0.f, 0.f, 0.f, 0.f, 0.f, 0.f};

    int kk = beg;
    for (; kk + 3 < end; kk += 4) {
        int n0 = edge_src[kk], n1 = edge_src[kk + 1];
        int n2 = edge_src[kk + 2], n3 = edge_src[kk + 3];
        if (active) {
            bf16x8 v0 = *(const bf16x8*)(Xbf + (size_t)n0 * GK + co);
            bf16x8 v1 = *(const bf16x8*)(Xbf + (size_t)n1 * GK + co);
            bf16x8 v2 = *(const bf16x8*)(Xbf + (size_t)n2 * GK + co);
            bf16x8 v3 = *(const bf16x8*)(Xbf + (size_t)n3 * GK + co);
#pragma unroll
            for (int j = 0; j < 8; ++j)
                acc[j] += ((float)v0[j] + (float)v1[j]) + ((float)v2[j] + (float)v3[j]);
        }
    }
    for (; kk < end; ++kk) {
        int n0 = edge_src[kk];
        if (active) {
            bf16x8 v = *(const bf16x8*)(Xbf + (size_t)n0 * GK + co);
#pragma unroll
            for (int j = 0; j < 8; ++j) acc[j] += (float)v[j];
        }
    }

    // fold fp32 noise via window-select (block-uniform d)
    if (active) {
        float nq[12];
        *(f32x4*)&nq[0] = na; *(f32x4*)&nq[4] = nb; *(f32x4*)&nq[8] = nc;
        if (t < 179) {
            switch (d) {
            case 0:
#pragma unroll
                for (int j = 0; j < 8; ++j) acc[j] += nq[0 + j];
                break;
            case 1:
#pragma unroll
                for (int j = 0; j < 8; ++j) acc[j] += nq[1 + j];
                break;
            case 2:
#pragma unroll
                for (int j = 0; j < 8; ++j) acc[j] += nq[2 + j];
                break;
            default:
#pragma unroll
                for (int j = 0; j < 8; ++j) acc[j] += nq[3 + j];
                break;
            }
        } else {                      // t == 179: only float col 1432 is real
            acc[0] += nq[8 + d];
        }
    }

    float ss = 0.f;
    if (active) {
        bf16x8 o;
#pragma unroll
        for (int j = 0; j < 8; ++j) { o[j] = (__bf16)acc[j]; ss += acc[j] * acc[j]; }
        *(bf16x8*)(aggbf + (size_t)node * GK + co) = o;
    }
    for (int off = 32; off > 0; off >>= 1) ss += __shfl_down(ss, off, 64);
    if ((t & 63) == 0) red[t >> 6] = ss;
    __syncthreads();
    if (t == 0)
        rnorm[node] = 1.0f / fmaxf(sqrtf(red[0] + red[1] + red[2]), 1e-12f);
}

// ---------------- bf16 MFMA GEMM: out = (aggbf @ WbfT^T) * rnorm + bias --------
// BM=128, BN=64, BK=32: 316 blocks; 4 waves, each 32x64 (2x4 of 16x16x32)

#define BK 32

__global__ void __launch_bounds__(256) k_gemm(const __bf16* __restrict__ A,
                                              const __bf16* __restrict__ BT,
                                              const float* __restrict__ rnorm,
                                              const float* __restrict__ bias,
                                              float* __restrict__ out) {
    __shared__ __align__(16) __bf16 Asm[128][BK];
    __shared__ __align__(16) __bf16 Bsm[64][BK];

    const int t = threadIdx.x;
    const int lane = t & 63;
    const int w = t >> 6;
    const int row0 = blockIdx.y * 128;
    const int col0 = blockIdx.x * 64;

    const int sm = t >> 2;        // 0..63
    const int sc = (t & 3) * 8;

    f32x4 acc[2][4];
#pragma unroll
    for (int i = 0; i < 2; ++i)
#pragma unroll
        for (int j = 0; j < 4; ++j) acc[i][j] = (f32x4){0.f, 0.f, 0.f, 0.f};

    __bf16* asm0 = (__bf16*)Asm;
    __bf16* bsm0 = (__bf16*)Bsm;

#pragma unroll
    for (int r = 0; r < 2; ++r)
        stage16(A + (size_t)(row0 + sm + r * 64) * GK + sc, asm0 + r * 2048 + t * 8);
    stage16(BT + (size_t)(col0 + sm) * GK + sc, bsm0 + t * 8);

    const int kq = (lane >> 4) * 8;
    const int l15 = lane & 15;

    for (int kt = 0; kt < GK / BK; ++kt) {
        __syncthreads();

        bf16x8 af[2], bfr[4];
#pragma unroll
        for (int i = 0; i < 2; ++i) af[i]  = *(const bf16x8*)&Asm[w * 32 + i * 16 + l15][kq];
#pragma unroll
        for (int j = 0; j < 4; ++j) bfr[j] = *(const bf16x8*)&Bsm[j * 16 + l15][kq];

        __syncthreads();

        if (kt + 1 < GK / BK) {
            int k0 = (kt + 1) * BK;
#pragma unroll
            for (int r = 0; r < 2; ++r)
                stage16(A + (size_t)(row0 + sm + r * 64) * GK + k0 + sc, asm0 + r * 2048 + t * 8);
            stage16(BT + (size_t)(col0 + sm) * GK + k0 + sc, bsm0 + t * 8);
        }

#pragma unroll
        for (int i = 0; i < 2; ++i)
#pragma unroll
            for (int j = 0; j < 4; ++j)
                acc[i][j] = __builtin_amdgcn_mfma_f32_16x16x32_bf16(af[i], bfr[j], acc[i][j], 0, 0, 0);
    }

    // epilogue: C/D layout col=lane&15, row=(lane>>4)*4+reg; fuse rnorm + bias
    const int rq4 = (lane >> 4) * 4;
#pragma unroll
    for (int i = 0; i < 2; ++i) {
        int gr0 = row0 + w * 32 + i * 16 + rq4;
#pragma unroll
        for (int r = 0; r < 4; ++r) {
            int gr = gr0 + r;
            if (gr < N_NODES) {
                float rn = rnorm[gr];
#pragma unroll
                for (int j = 0; j < 4; ++j) {
                    int gc = col0 + j * 16 + l15;
                    out[(size_t)gr * OUT_F + gc] = acc[i][j][r] * rn + bias[gc];
                }
            }
        }
    }
}

// ---------------- launch ----------------

extern "C" void kernel_launch(void* const* d_in, const int* in_sizes, int n_in,
                              void* d_out, int out_size, void* d_ws, size_t ws_size,
                              hipStream_t stream) {
    const float* feat  = (const float*)d_in[0];
    const int*   edges = (const int*)d_in[1];
    const float* W     = (const float*)d_in[2];
    const float* bias  = (const float*)d_in[3];
    const float* noise = (const float*)d_in[4];
    float* out = (float*)d_out;

    char* ws = (char*)d_ws;
    size_t off = 0;
    auto carve = [&](size_t bytes) {
        void* p = ws + off;
        off = (off + bytes + 255) & ~(size_t)255;
        return p;
    };
    __bf16* Xbf     = (__bf16*)carve((size_t)N_NODES * GK * sizeof(__bf16));
    __bf16* aggbf   = (__bf16*)carve((size_t)GM2 * GK * sizeof(__bf16));
    __bf16* WbfT    = (__bf16*)carve((size_t)OUT_F * GK * sizeof(__bf16));
    float*  rnorm   = (float*)carve((size_t)N_NODES * sizeof(float));
    int*    offsets = (int*)carve((size_t)(N_NODES + 1) * sizeof(int));
    int*    edge_src= (int*)carve((size_t)N_EDGES * sizeof(int));
    (void)ws_size;

    k_phaseA<<<PHASEA_BLKS, 256, 0, stream>>>(feat, Xbf, W, WbfT,
                                              edges, offsets, edge_src);

    k_agg<<<GM2, 192, 0, stream>>>(Xbf, noise, offsets, edge_src, aggbf, rnorm);

    dim3 ggrid(OUT_F / 64, GM2 / 128);
    k_gemm<<<ggrid, 256, 0, stream>>>(aggbf, WbfT, rnorm, bias, out);
}

// Round 4
// 211.019 us; speedup vs baseline: 1.7080x; 1.7080x over previous
//
#include <hip/hip_runtime.h>
#include <math.h>

#define N_NODES 10000
#define N_EDGES 50000
#define IN_F    1433
#define OUT_F   256
#define GK      1440          // padded K: multiple of 32, rows 16B-aligned
#define NCHUNK  180           // GK/8
#define GM2     10112         // 79*128: agg rows padded to GEMM M tiles

typedef __bf16 bf16x8 __attribute__((ext_vector_type(8)));
typedef float  f32x4  __attribute__((ext_vector_type(4)));

typedef __attribute__((address_space(3))) unsigned int lds_u32;
typedef __attribute__((address_space(1))) unsigned int glb_u32;

__device__ __forceinline__ void stage16(const void* g, void* l) {
    __builtin_amdgcn_global_load_lds((glb_u32*)g, (lds_u32*)l, 16, 0, 0);
}

// ---------------- phase A: conv + prep + hist in ONE dispatch ----------------
// blocks [0, 2500)        : fp32->bf16 convert of X (4 rows/block, window-select)
// blocks [2500, 3940)     : W^T prep (bf16, zero-padded K)
// blocks [3940, 4136)     : edge histogram via GLOBAL atomics (one edge/thread;
//                           latency hidden by the conv blocks' BW window).
// NO LDS anywhere -> conv occupancy unconstrained. Single-block CSR was the
// round-3 regression: 4 waves x 2x196 serialized global-latency iterations
// = 190 us tail at 4% occupancy. Parallel hist + tiny scan/fill dispatches
// hide the same work under conv.
//
// conv window-select: wave w owns row r = b*4 + w; row start mod 4 == r&3
// == d (1433 % 4 == 1) -> uniform branch picks dwords [d..d+7] from 3 aligned
// float4 loads, ALL hoisted up front (one latency per row, not three).
// Loads clamp chunk to 178; chunk 178's 12-float window ends at col 1432
// (worst: row 9999, d=3 lands exactly on the last element 14,329,999).
// Chunk 179's single valid float (col 1432) sits at q[8+d] of that window.

#define PREP_W      (OUT_F * GK)         // 368640 = 1440 blocks * 256
#define CONV_BLKS   (N_NODES / 4)        // 2500
#define PREP_BLKS   (PREP_W / 256)       // 1440
#define HIST_BLKS   ((N_EDGES + 255) / 256)   // 196
#define PHASEA_BLKS (CONV_BLKS + PREP_BLKS + HIST_BLKS)

__global__ void __launch_bounds__(256) k_phaseA(const float* __restrict__ X,
                                                __bf16* __restrict__ Xbf,
                                                const float* __restrict__ W,
                                                __bf16* __restrict__ BT,
                                                const int* __restrict__ edges,
                                                int* __restrict__ counts) {
    const int t = threadIdx.x;
    const int b = blockIdx.x;

    if (b < CONV_BLKS) {
        // ---- conv: fp32 -> bf16, ILP-hoisted window-select ----
        const int w = t >> 6, lane = t & 63;
        const int r = b * 4 + w;                     // 0..9999
        const size_t rowf = (size_t)r * IN_F;
        __bf16* orow = Xbf + (size_t)r * GK;
        const int d = r & 3;

        f32x4 A[3][3];
#pragma unroll
        for (int s2 = 0; s2 < 3; ++s2) {
            int k = lane + s2 * 64;
            int kc = (k > 178) ? 178 : k;            // clamped: always in-bounds
            size_t q0 = (rowf + (size_t)kc * 8) >> 2;
            A[s2][0] = ((const f32x4*)X)[q0];
            A[s2][1] = ((const f32x4*)X)[q0 + 1];
            A[s2][2] = ((const f32x4*)X)[q0 + 2];
        }

#pragma unroll
        for (int s2 = 0; s2 < 3; ++s2) {
            int k = lane + s2 * 64;
            float q[12];
            *(f32x4*)&q[0] = A[s2][0];
            *(f32x4*)&q[4] = A[s2][1];
            *(f32x4*)&q[8] = A[s2][2];
            if (k < 179) {
                bf16x8 v;
                switch (d) {                          // wave-uniform
                case 0:
#pragma unroll
                    for (int j = 0; j < 8; ++j) v[j] = (__bf16)q[0 + j];
                    break;
                case 1:
#pragma unroll
                    for (int j = 0; j < 8; ++j) v[j] = (__bf16)q[1 + j];
                    break;
                case 2:
#pragma unroll
                    for (int j = 0; j < 8; ++j) v[j] = (__bf16)q[2 + j];
                    break;
                default:
#pragma unroll
                    for (int j = 0; j < 8; ++j) v[j] = (__bf16)q[3 + j];
                    break;
                }
                *(bf16x8*)(orow + k * 8) = v;
            } else if (k == 179) {
                bf16x8 v;
                v[0] = (__bf16)q[8 + d];              // float col 1432
#pragma unroll
                for (int j = 1; j < 8; ++j) v[j] = (__bf16)0.0f;
                *(bf16x8*)(orow + 1432) = v;
            }
        }
        return;
    }

    if (b < CONV_BLKS + PREP_BLKS) {
        // ---- prep: W^T (bf16, zero-padded K) ----
        int i = (b - CONV_BLKS) * 256 + t;            // 0..368639
        int n = i / GK, k = i % GK;
        BT[i] = (__bf16)((k < IN_F) ? W[(size_t)k * OUT_F + n] : 0.0f);
        return;
    }

    // ---- hist: one edge per thread, global atomics ----
    {
        int e = (b - CONV_BLKS - PREP_BLKS) * 256 + t;
        if (e < N_EDGES) {
            int dst = edges[2 * e];
            int src = edges[2 * e + 1];
            if ((unsigned)src < N_NODES) atomicAdd(&counts[dst], 1);
        }
    }
}

// shuffle-based single-block scan: 3 syncs per 1024-chunk (10 chunks, trivial)
__global__ void __launch_bounds__(1024) k_scan(const int* __restrict__ counts,
                                               int* __restrict__ offsets,
                                               int* __restrict__ cursor) {
    __shared__ int wsum[16];
    __shared__ int carry_s;
    const int t = threadIdx.x, lane = t & 63, wid = t >> 6;
    if (t == 0) carry_s = 0;
    __syncthreads();
    for (int base = 0; base < N_NODES; base += 1024) {
        int i = base + t;
        int v = (i < N_NODES) ? counts[i] : 0;
        int s = v;
#pragma unroll
        for (int off = 1; off < 64; off <<= 1) {
            int u = __shfl_up(s, off, 64);
            if (lane >= off) s += u;
        }
        if (lane == 63) wsum[wid] = s;
        __syncthreads();
        if (t == 0) {
            int run = carry_s;
#pragma unroll
            for (int w2 = 0; w2 < 16; ++w2) { int tmp = wsum[w2]; wsum[w2] = run; run += tmp; }
            carry_s = run;
        }
        __syncthreads();
        int excl = wsum[wid] + s - v;
        if (i < N_NODES) { offsets[i] = excl; cursor[i] = excl; }
        __syncthreads();
    }
    if (t == 0) offsets[N_NODES] = carry_s;
}

__global__ void k_fill(const int* __restrict__ edges, int* __restrict__ cursor,
                       int* __restrict__ edge_src) {
    int e = blockIdx.x * blockDim.x + threadIdx.x;
    if (e < N_EDGES) {
        int dst = edges[2 * e];
        int src = edges[2 * e + 1];
        if ((unsigned)src < N_NODES) {
            int pos = atomicAdd(&cursor[dst], 1);
            edge_src[pos] = src;
        }
    }
}

// ---------------- aggregate: barrier-free, bf16x8 gathers + fp32 noise init ---
// agg[i] = noise[i] + sum_{src in N(i)} X[src];  rnorm[i] = 1/max(||agg||,1e-12)
// noise is read DIRECTLY as fp32 with the same window-select (d = node&3 is
// block-uniform); its 3 loads are issued before the gather loop so they fly
// under it. grid = GM2: blocks >= N_NODES just zero their pad row.

__global__ void __launch_bounds__(192) k_agg(const __bf16* __restrict__ Xbf,
                                             const float* __restrict__ noise,
                                             const int* __restrict__ offsets,
                                             const int* __restrict__ edge_src,
                                             __bf16* __restrict__ aggbf,
                                             float* __restrict__ rnorm) {
    __shared__ float red[3];
    const int node = blockIdx.x;
    const int t = threadIdx.x;
    const bool active = (t < NCHUNK);
    const size_t co = (size_t)t * 8;

    if (node >= N_NODES) {          // pad rows for the GEMM M-tiling
        if (active) {
            bf16x8 z;
#pragma unroll
            for (int j = 0; j < 8; ++j) z[j] = (__bf16)0.0f;
            *(bf16x8*)(aggbf + (size_t)node * GK + co) = z;
        }
        return;
    }

    // issue noise window loads early (fp32, clamped chunk <= 178: in-bounds,
    // see k_phaseA conv comment)
    const size_t nrowf = (size_t)node * IN_F;
    const int d = node & 3;
    f32x4 na, nb, nc;
    if (active) {
        int kc = (t > 178) ? 178 : t;
        size_t q0 = (nrowf + (size_t)kc * 8) >> 2;
        na = ((const f32x4*)noise)[q0];
        nb = ((const f32x4*)noise)[q0 + 1];
        nc = ((const f32x4*)noise)[q0 + 2];
    }

    const int beg = offsets[node], end = offsets[node + 1];

    float acc[8] = {0.f, 0.f, 0.f, 0.f, 0.f, 0.f, 0.f, 0.f};

    int kk = beg;
    for (; kk + 3 < end; kk += 4) {
        int n0 = edge_src[kk], n1 = edge_src[kk + 1];
        int n2 = edge_src[kk + 2], n3 = edge_src[kk + 3];
        if (active) {
            bf16x8 v0 = *(const bf16x8*)(Xbf + (size_t)n0 * GK + co);
            bf16x8 v1 = *(const bf16x8*)(Xbf + (size_t)n1 * GK + co);
            bf16x8 v2 = *(const bf16x8*)(Xbf + (size_t)n2 * GK + co);
            bf16x8 v3 = *(const bf16x8*)(Xbf + (size_t)n3 * GK + co);
#pragma unroll
            for (int j = 0; j < 8; ++j)
                acc[j] += ((float)v0[j] + (float)v1[j]) + ((float)v2[j] + (float)v3[j]);
        }
    }
    for (; kk < end; ++kk) {
        int n0 = edge_src[kk];
        if (active) {
            bf16x8 v = *(const bf16x8*)(Xbf + (size_t)n0 * GK + co);
#pragma unroll
            for (int j = 0; j < 8; ++j) acc[j] += (float)v[j];
        }
    }

    // fold fp32 noise via window-select (block-uniform d)
    if (active) {
        float nq[12];
        *(f32x4*)&nq[0] = na; *(f32x4*)&nq[4] = nb; *(f32x4*)&nq[8] = nc;
        if (t < 179) {
            switch (d) {
            case 0:
#pragma unroll
                for (int j = 0; j < 8; ++j) acc[j] += nq[0 + j];
                break;
            case 1:
#pragma unroll
                for (int j = 0; j < 8; ++j) acc[j] += nq[1 + j];
                break;
            case 2:
#pragma unroll
                for (int j = 0; j < 8; ++j) acc[j] += nq[2 + j];
                break;
            default:
#pragma unroll
                for (int j = 0; j < 8; ++j) acc[j] += nq[3 + j];
                break;
            }
        } else {                      // t == 179: only float col 1432 is real
            acc[0] += nq[8 + d];
        }
    }

    float ss = 0.f;
    if (active) {
        bf16x8 o;
#pragma unroll
        for (int j = 0; j < 8; ++j) { o[j] = (__bf16)acc[j]; ss += acc[j] * acc[j]; }
        *(bf16x8*)(aggbf + (size_t)node * GK + co) = o;
    }
    for (int off = 32; off > 0; off >>= 1) ss += __shfl_down(ss, off, 64);
    if ((t & 63) == 0) red[t >> 6] = ss;
    __syncthreads();
    if (t == 0)
        rnorm[node] = 1.0f / fmaxf(sqrtf(red[0] + red[1] + red[2]), 1e-12f);
}

// ---------------- bf16 MFMA GEMM: out = (aggbf @ WbfT^T) * rnorm + bias --------
// BM=128, BN=64, BK=32: 316 blocks; 4 waves, each 32x64 (2x4 of 16x16x32)

#define BK 32

__global__ void __launch_bounds__(256) k_gemm(const __bf16* __restrict__ A,
                                              const __bf16* __restrict__ BT,
                                              const float* __restrict__ rnorm,
                                              const float* __restrict__ bias,
                                              float* __restrict__ out) {
    __shared__ __align__(16) __bf16 Asm[128][BK];
    __shared__ __align__(16) __bf16 Bsm[64][BK];

    const int t = threadIdx.x;
    const int lane = t & 63;
    const int w = t >> 6;
    const int row0 = blockIdx.y * 128;
    const int col0 = blockIdx.x * 64;

    const int sm = t >> 2;        // 0..63
    const int sc = (t & 3) * 8;

    f32x4 acc[2][4];
#pragma unroll
    for (int i = 0; i < 2; ++i)
#pragma unroll
        for (int j = 0; j < 4; ++j) acc[i][j] = (f32x4){0.f, 0.f, 0.f, 0.f};

    __bf16* asm0 = (__bf16*)Asm;
    __bf16* bsm0 = (__bf16*)Bsm;

#pragma unroll
    for (int r = 0; r < 2; ++r)
        stage16(A + (size_t)(row0 + sm + r * 64) * GK + sc, asm0 + r * 2048 + t * 8);
    stage16(BT + (size_t)(col0 + sm) * GK + sc, bsm0 + t * 8);

    const int kq = (lane >> 4) * 8;
    const int l15 = lane & 15;

    for (int kt = 0; kt < GK / BK; ++kt) {
        __syncthreads();

        bf16x8 af[2], bfr[4];
#pragma unroll
        for (int i = 0; i < 2; ++i) af[i]  = *(const bf16x8*)&Asm[w * 32 + i * 16 + l15][kq];
#pragma unroll
        for (int j = 0; j < 4; ++j) bfr[j] = *(const bf16x8*)&Bsm[j * 16 + l15][kq];

        __syncthreads();

        if (kt + 1 < GK / BK) {
            int k0 = (kt + 1) * BK;
#pragma unroll
            for (int r = 0; r < 2; ++r)
                stage16(A + (size_t)(row0 + sm + r * 64) * GK + k0 + sc, asm0 + r * 2048 + t * 8);
            stage16(BT + (size_t)(col0 + sm) * GK + k0 + sc, bsm0 + t * 8);
        }

#pragma unroll
        for (int i = 0; i < 2; ++i)
#pragma unroll
            for (int j = 0; j < 4; ++j)
                acc[i][j] = __builtin_amdgcn_mfma_f32_16x16x32_bf16(af[i], bfr[j], acc[i][j], 0, 0, 0);
    }

    // epilogue: C/D layout col=lane&15, row=(lane>>4)*4+reg; fuse rnorm + bias
    const int rq4 = (lane >> 4) * 4;
#pragma unroll
    for (int i = 0; i < 2; ++i) {
        int gr0 = row0 + w * 32 + i * 16 + rq4;
#pragma unroll
        for (int r = 0; r < 4; ++r) {
            int gr = gr0 + r;
            if (gr < N_NODES) {
                float rn = rnorm[gr];
#pragma unroll
                for (int j = 0; j < 4; ++j) {
                    int gc = col0 + j * 16 + l15;
                    out[(size_t)gr * OUT_F + gc] = acc[i][j][r] * rn + bias[gc];
                }
            }
        }
    }
}

// ---------------- launch ----------------

extern "C" void kernel_launch(void* const* d_in, const int* in_sizes, int n_in,
                              void* d_out, int out_size, void* d_ws, size_t ws_size,
                              hipStream_t stream) {
    const float* feat  = (const float*)d_in[0];
    const int*   edges = (const int*)d_in[1];
    const float* W     = (const float*)d_in[2];
    const float* bias  = (const float*)d_in[3];
    const float* noise = (const float*)d_in[4];
    float* out = (float*)d_out;

    char* ws = (char*)d_ws;
    size_t off = 0;
    auto carve = [&](size_t bytes) {
        void* p = ws + off;
        off = (off + bytes + 255) & ~(size_t)255;
        return p;
    };
    __bf16* Xbf     = (__bf16*)carve((size_t)N_NODES * GK * sizeof(__bf16));
    __bf16* aggbf   = (__bf16*)carve((size_t)GM2 * GK * sizeof(__bf16));
    __bf16* WbfT    = (__bf16*)carve((size_t)OUT_F * GK * sizeof(__bf16));
    float*  rnorm   = (float*)carve((size_t)N_NODES * sizeof(float));
    int*    counts  = (int*)carve((size_t)(N_NODES + 1) * sizeof(int));
    int*    offsets = (int*)carve((size_t)(N_NODES + 1) * sizeof(int));
    int*    cursor  = (int*)carve((size_t)(N_NODES + 1) * sizeof(int));
    int*    edge_src= (int*)carve((size_t)N_EDGES * sizeof(int));
    (void)ws_size;

    const int TB = 256;
    hipMemsetAsync(counts, 0, (size_t)(N_NODES + 1) * sizeof(int), stream);

    k_phaseA<<<PHASEA_BLKS, 256, 0, stream>>>(feat, Xbf, W, WbfT, edges, counts);

    k_scan<<<1, 1024, 0, stream>>>(counts, offsets, cursor);
    k_fill<<<(N_EDGES + TB - 1) / TB, TB, 0, stream>>>(edges, cursor, edge_src);

    k_agg<<<GM2, 192, 0, stream>>>(Xbf, noise, offsets, edge_src, aggbf, rnorm);

    dim3 ggrid(OUT_F / 64, GM2 / 128);
    k_gemm<<<ggrid, 256, 0, stream>>>(aggbf, WbfT, rnorm, bias, out);
}

// Round 5
// 193.600 us; speedup vs baseline: 1.8617x; 1.0900x over previous
//
#include <hip/hip_runtime.h>
#include <math.h>

#define N_NODES 10000
#define N_EDGES 50000
#define IN_F    1433
#define OUT_F   256
#define GK      1440          // padded K: multiple of 32, rows 16B-aligned
#define NCHUNK  180           // GK/8
#define GM2     10112         // 79*128: agg rows padded to GEMM M tiles
#define CAP     32            // fixed slots per node; overflow list handles the rest

typedef __bf16 bf16x8 __attribute__((ext_vector_type(8)));
typedef float  f32x4  __attribute__((ext_vector_type(4)));

typedef __attribute__((address_space(3))) unsigned int lds_u32;
typedef __attribute__((address_space(1))) unsigned int glb_u32;

__device__ __forceinline__ void stage16(const void* g, void* l) {
    __builtin_amdgcn_global_load_lds((glb_u32*)g, (lds_u32*)l, 16, 0, 0);
}

// ---------------- phase A: fill + conv + prep in ONE dispatch ----------------
// blocks [0, 196)          : edge binning -- ONE pass, no scan needed:
//                            pos = atomicAdd(&cnt[dst],1); pos<CAP -> slot,
//                            else overflow list (cnt[N_NODES] = ovf count).
//                            Placed FIRST so the latency-bound atomics start
//                            early and finish under the conv BW window.
// blocks [196, 2696)       : fp32->bf16 convert of X (4 rows/block)
// blocks [2696, 4136)      : W^T prep (bf16, zero-padded K)
// NO LDS anywhere -> conv occupancy unconstrained (round-3 lesson: the 1-block
// CSR tail ran 190 us at 4% occupancy; slot binning keeps every stage wide).
//
// conv window-select: wave w owns row r; row start mod 4 == r&3 == d
// (1433 % 4 == 1) -> uniform branch picks dwords [d..d+7] from 3 aligned
// float4 loads, ALL hoisted up front (one latency per row, not three).
// Loads clamp chunk to 178; chunk 178's 12-float window ends at col 1432
// (worst: row 9999, d=3 lands exactly on the last element 14,329,999).
// Chunk 179's single valid float (col 1432) sits at q[8+d] of that window.

#define PREP_W      (OUT_F * GK)              // 368640 = 1440 blocks * 256
#define FILL_BLKS   ((N_EDGES + 255) / 256)   // 196
#define CONV_BLKS   (N_NODES / 4)             // 2500
#define PREP_BLKS   (PREP_W / 256)            // 1440
#define PHASEA_BLKS (FILL_BLKS + CONV_BLKS + PREP_BLKS)

__global__ void __launch_bounds__(256) k_phaseA(const float* __restrict__ X,
                                                __bf16* __restrict__ Xbf,
                                                const float* __restrict__ W,
                                                __bf16* __restrict__ BT,
                                                const int* __restrict__ edges,
                                                int* __restrict__ cnt,
                                                int* __restrict__ slots,
                                                int* __restrict__ ovf) {
    const int t = threadIdx.x;
    const int b = blockIdx.x;

    if (b < FILL_BLKS) {
        // ---- edge binning: hist+fill collapsed into one atomic pass ----
        int e = b * 256 + t;
        if (e < N_EDGES) {
            int dst = edges[2 * e];
            int src = edges[2 * e + 1];
            if ((unsigned)src < N_NODES) {
                int pos = atomicAdd(&cnt[dst], 1);
                if (pos < CAP) {
                    slots[dst * CAP + pos] = src;
                } else {
                    int o = atomicAdd(&cnt[N_NODES], 1);
                    ovf[2 * o]     = dst;
                    ovf[2 * o + 1] = src;
                }
            }
        }
        return;
    }

    if (b < FILL_BLKS + CONV_BLKS) {
        // ---- conv: fp32 -> bf16, ILP-hoisted window-select ----
        const int w = t >> 6, lane = t & 63;
        const int r = (b - FILL_BLKS) * 4 + w;       // 0..9999
        const size_t rowf = (size_t)r * IN_F;
        __bf16* orow = Xbf + (size_t)r * GK;
        const int d = r & 3;

        f32x4 A[3][3];
#pragma unroll
        for (int s2 = 0; s2 < 3; ++s2) {
            int k = lane + s2 * 64;
            int kc = (k > 178) ? 178 : k;            // clamped: always in-bounds
            size_t q0 = (rowf + (size_t)kc * 8) >> 2;
            A[s2][0] = ((const f32x4*)X)[q0];
            A[s2][1] = ((const f32x4*)X)[q0 + 1];
            A[s2][2] = ((const f32x4*)X)[q0 + 2];
        }

#pragma unroll
        for (int s2 = 0; s2 < 3; ++s2) {
            int k = lane + s2 * 64;
            float q[12];
            *(f32x4*)&q[0] = A[s2][0];
            *(f32x4*)&q[4] = A[s2][1];
            *(f32x4*)&q[8] = A[s2][2];
            if (k < 179) {
                bf16x8 v;
                switch (d) {                          // wave-uniform
                case 0:
#pragma unroll
                    for (int j = 0; j < 8; ++j) v[j] = (__bf16)q[0 + j];
                    break;
                case 1:
#pragma unroll
                    for (int j = 0; j < 8; ++j) v[j] = (__bf16)q[1 + j];
                    break;
                case 2:
#pragma unroll
                    for (int j = 0; j < 8; ++j) v[j] = (__bf16)q[2 + j];
                    break;
                default:
#pragma unroll
                    for (int j = 0; j < 8; ++j) v[j] = (__bf16)q[3 + j];
                    break;
                }
                *(bf16x8*)(orow + k * 8) = v;
            } else if (k == 179) {
                bf16x8 v;
                v[0] = (__bf16)q[8 + d];              // float col 1432
#pragma unroll
                for (int j = 1; j < 8; ++j) v[j] = (__bf16)0.0f;
                *(bf16x8*)(orow + 1432) = v;
            }
        }
        return;
    }

    // ---- prep: W^T (bf16, zero-padded K) ----
    {
        int i = (b - FILL_BLKS - CONV_BLKS) * 256 + t;   // 0..368639
        int n = i / GK, k = i % GK;
        BT[i] = (__bf16)((k < IN_F) ? W[(size_t)k * OUT_F + n] : 0.0f);
    }
}

// ---------------- aggregate: slot-list gathers + fp32 noise init --------------
// agg[i] = noise[i] + sum_{src in N(i)} X[src];  rnorm[i] = 1/max(||agg||,1e-12)
// Neighbor list = slots[node*CAP .. node*CAP+min(cn,CAP)) plus (rare) overflow
// entries with dst==node. Slot reads are wave-uniform -> scalar broadcast,
// same cost as the old CSR edge_src reads. noise read DIRECTLY as fp32 with
// the window-select (d = node&3 block-uniform), loads issued before the
// gather loop so they fly under it. grid = GM2: pad rows just write zero.

__global__ void __launch_bounds__(192) k_agg(const __bf16* __restrict__ Xbf,
                                             const float* __restrict__ noise,
                                             const int* __restrict__ cnt,
                                             const int* __restrict__ slots,
                                             const int* __restrict__ ovf,
                                             __bf16* __restrict__ aggbf,
                                             float* __restrict__ rnorm) {
    __shared__ float red[3];
    const int node = blockIdx.x;
    const int t = threadIdx.x;
    const bool active = (t < NCHUNK);
    const size_t co = (size_t)t * 8;

    if (node >= N_NODES) {          // pad rows for the GEMM M-tiling
        if (active) {
            bf16x8 z;
#pragma unroll
            for (int j = 0; j < 8; ++j) z[j] = (__bf16)0.0f;
            *(bf16x8*)(aggbf + (size_t)node * GK + co) = z;
        }
        return;
    }

    // issue noise window loads early (fp32, clamped chunk <= 178: in-bounds,
    // see k_phaseA conv comment)
    const size_t nrowf = (size_t)node * IN_F;
    const int d = node & 3;
    f32x4 na, nb, nc;
    if (active) {
        int kc = (t > 178) ? 178 : t;
        size_t q0 = (nrowf + (size_t)kc * 8) >> 2;
        na = ((const f32x4*)noise)[q0];
        nb = ((const f32x4*)noise)[q0 + 1];
        nc = ((const f32x4*)noise)[q0 + 2];
    }

    const int cn = cnt[node];
    const int ns = (cn < CAP) ? cn : CAP;
    const int* sl = slots + node * CAP;

    float acc[8] = {0.f, 0.f, 0.f, 0.f, 0.f, 0.f, 0.f, 0.f};

    int kk = 0;
    for (; kk + 3 < ns; kk += 4) {
        int n0 = sl[kk], n1 = sl[kk + 1];
        int n2 = sl[kk + 2], n3 = sl[kk + 3];
        if (active) {
            bf16x8 v0 = *(const bf16x8*)(Xbf + (size_t)n0 * GK + co);
            bf16x8 v1 = *(const bf16x8*)(Xbf + (size_t)n1 * GK + co);
            bf16x8 v2 = *(const bf16x8*)(Xbf + (size_t)n2 * GK + co);
            bf16x8 v3 = *(const bf16x8*)(Xbf + (size_t)n3 * GK + co);
#pragma unroll
            for (int j = 0; j < 8; ++j)
                acc[j] += ((float)v0[j] + (float)v1[j]) + ((float)v2[j] + (float)v3[j]);
        }
    }
    for (; kk < ns; ++kk) {
        int n0 = sl[kk];
        if (active) {
            bf16x8 v = *(const bf16x8*)(Xbf + (size_t)n0 * GK + co);
#pragma unroll
            for (int j = 0; j < 8; ++j) acc[j] += (float)v[j];
        }
    }

    if (cn > CAP) {                  // exact overflow path (rare/never)
        const int L = cnt[N_NODES];
        for (int i = 0; i < L; ++i) {
            if (ovf[2 * i] == node) {
                int n0 = ovf[2 * i + 1];
                if (active) {
                    bf16x8 v = *(const bf16x8*)(Xbf + (size_t)n0 * GK + co);
#pragma unroll
                    for (int j = 0; j < 8; ++j) acc[j] += (float)v[j];
                }
            }
        }
    }

    // fold fp32 noise via window-select (block-uniform d)
    if (active) {
        float nq[12];
        *(f32x4*)&nq[0] = na; *(f32x4*)&nq[4] = nb; *(f32x4*)&nq[8] = nc;
        if (t < 179) {
            switch (d) {
            case 0:
#pragma unroll
                for (int j = 0; j < 8; ++j) acc[j] += nq[0 + j];
                break;
            case 1:
#pragma unroll
                for (int j = 0; j < 8; ++j) acc[j] += nq[1 + j];
                break;
            case 2:
#pragma unroll
                for (int j = 0; j < 8; ++j) acc[j] += nq[2 + j];
                break;
            default:
#pragma unroll
                for (int j = 0; j < 8; ++j) acc[j] += nq[3 + j];
                break;
            }
        } else {                      // t == 179: only float col 1432 is real
            acc[0] += nq[8 + d];
        }
    }

    float ss = 0.f;
    if (active) {
        bf16x8 o;
#pragma unroll
        for (int j = 0; j < 8; ++j) { o[j] = (__bf16)acc[j]; ss += acc[j] * acc[j]; }
        *(bf16x8*)(aggbf + (size_t)node * GK + co) = o;
    }
    for (int off = 32; off > 0; off >>= 1) ss += __shfl_down(ss, off, 64);
    if ((t & 63) == 0) red[t >> 6] = ss;
    __syncthreads();
    if (t == 0)
        rnorm[node] = 1.0f / fmaxf(sqrtf(red[0] + red[1] + red[2]), 1e-12f);
}

// ---------------- bf16 MFMA GEMM: out = (aggbf @ WbfT^T) * rnorm + bias --------
// BM=128, BN=64, BK=32: 316 blocks; 4 waves, each 32x64 (2x4 of 16x16x32).
// 1D grid + bijective XCD chunk swizzle (m204 form): the 4 column-blocks that
// share one 128-row A panel (368 KB, fits a 4 MiB XCD L2) become CONSECUTIVE
// work items on the SAME XCD -> 3 of the 4 A-panel reads hit that XCD's L2
// instead of refetching from L3. Bijective for nwg=316 (q=39, r=4); any
// dispatch->XCD mapping change affects only locality, never correctness.

#define BK 32
#define GEMM_NWG ((GM2 / 128) * (OUT_F / 64))   // 316

__global__ void __launch_bounds__(256) k_gemm(const __bf16* __restrict__ A,
                                              const __bf16* __restrict__ BT,
                                              const float* __restrict__ rnorm,
                                              const float* __restrict__ bias,
                                              float* __restrict__ out) {
    __shared__ __align__(16) __bf16 Asm[128][BK];
    __shared__ __align__(16) __bf16 Bsm[64][BK];

    const int t = threadIdx.x;
    const int lane = t & 63;
    const int w = t >> 6;

    // XCD-bijective swizzle: dispatch round-robins blockIdx%8 across XCDs.
    const int L   = blockIdx.x;
    const int xcd = L & 7, idx = L >> 3;
    const int q = GEMM_NWG >> 3, r = GEMM_NWG & 7;   // 39, 4
    const int work = (xcd < r) ? xcd * (q + 1) + idx
                               : r * (q + 1) + (xcd - r) * q + idx;
    const int row0 = (work >> 2) * 128;
    const int col0 = (work & 3) * 64;

    const int sm = t >> 2;        // 0..63
    const int sc = (t & 3) * 8;

    f32x4 acc[2][4];
#pragma unroll
    for (int i = 0; i < 2; ++i)
#pragma unroll
        for (int j = 0; j < 4; ++j) acc[i][j] = (f32x4){0.f, 0.f, 0.f, 0.f};

    __bf16* asm0 = (__bf16*)Asm;
    __bf16* bsm0 = (__bf16*)Bsm;

#pragma unroll
    for (int rr = 0; rr < 2; ++rr)
        stage16(A + (size_t)(row0 + sm + rr * 64) * GK + sc, asm0 + rr * 2048 + t * 8);
    stage16(BT + (size_t)(col0 + sm) * GK + sc, bsm0 + t * 8);

    const int kq = (lane >> 4) * 8;
    const int l15 = lane & 15;

    for (int kt = 0; kt < GK / BK; ++kt) {
        __syncthreads();

        bf16x8 af[2], bfr[4];
#pragma unroll
        for (int i = 0; i < 2; ++i) af[i]  = *(const bf16x8*)&Asm[w * 32 + i * 16 + l15][kq];
#pragma unroll
        for (int j = 0; j < 4; ++j) bfr[j] = *(const bf16x8*)&Bsm[j * 16 + l15][kq];

        __syncthreads();

        if (kt + 1 < GK / BK) {
            int k0 = (kt + 1) * BK;
#pragma unroll
            for (int rr = 0; rr < 2; ++rr)
                stage16(A + (size_t)(row0 + sm + rr * 64) * GK + k0 + sc, asm0 + rr * 2048 + t * 8);
            stage16(BT + (size_t)(col0 + sm) * GK + k0 + sc, bsm0 + t * 8);
        }

#pragma unroll
        for (int i = 0; i < 2; ++i)
#pragma unroll
            for (int j = 0; j < 4; ++j)
                acc[i][j] = __builtin_amdgcn_mfma_f32_16x16x32_bf16(af[i], bfr[j], acc[i][j], 0, 0, 0);
    }

    // epilogue: C/D layout col=lane&15, row=(lane>>4)*4+reg; fuse rnorm + bias
    const int rq4 = (lane >> 4) * 4;
#pragma unroll
    for (int i = 0; i < 2; ++i) {
        int gr0 = row0 + w * 32 + i * 16 + rq4;
#pragma unroll
        for (int rr = 0; rr < 4; ++rr) {
            int gr = gr0 + rr;
            if (gr < N_NODES) {
                float rn = rnorm[gr];
#pragma unroll
                for (int j = 0; j < 4; ++j) {
                    int gc = col0 + j * 16 + l15;
                    out[(size_t)gr * OUT_F + gc] = acc[i][j][rr] * rn + bias[gc];
                }
            }
        }
    }
}

// ---------------- launch ----------------

extern "C" void kernel_launch(void* const* d_in, const int* in_sizes, int n_in,
                              void* d_out, int out_size, void* d_ws, size_t ws_size,
                              hipStream_t stream) {
    const float* feat  = (const float*)d_in[0];
    const int*   edges = (const int*)d_in[1];
    const float* W     = (const float*)d_in[2];
    const float* bias  = (const float*)d_in[3];
    const float* noise = (const float*)d_in[4];
    float* out = (float*)d_out;

    char* ws = (char*)d_ws;
    size_t off = 0;
    auto carve = [&](size_t bytes) {
        void* p = ws + off;
        off = (off + bytes + 255) & ~(size_t)255;
        return p;
    };
    __bf16* Xbf     = (__bf16*)carve((size_t)N_NODES * GK * sizeof(__bf16));
    __bf16* aggbf   = (__bf16*)carve((size_t)GM2 * GK * sizeof(__bf16));
    __bf16* WbfT    = (__bf16*)carve((size_t)OUT_F * GK * sizeof(__bf16));
    float*  rnorm   = (float*)carve((size_t)N_NODES * sizeof(float));
    int*    cnt     = (int*)carve((size_t)(N_NODES + 1) * sizeof(int));   // +ovf count
    int*    slots   = (int*)carve((size_t)N_NODES * CAP * sizeof(int));
    int*    ovf     = (int*)carve((size_t)2 * N_EDGES * sizeof(int));
    (void)ws_size;

    hipMemsetAsync(cnt, 0, (size_t)(N_NODES + 1) * sizeof(int), stream);

    k_phaseA<<<PHASEA_BLKS, 256, 0, stream>>>(feat, Xbf, W, WbfT,
                                              edges, cnt, slots, ovf);

    k_agg<<<GM2, 192, 0, stream>>>(Xbf, noise, cnt, slots, ovf, aggbf, rnorm);

    k_gemm<<<GEMM_NWG, 256, 0, stream>>>(aggbf, WbfT, rnorm, bias, out);
}

// Round 6
// 183.972 us; speedup vs baseline: 1.9591x; 1.0523x over previous
//
#include <hip/hip_runtime.h>
#include <math.h>

#define N_NODES 10000
#define N_EDGES 50000
#define IN_F    1433
#define OUT_F   256
#define GK      1440          // padded K: multiple of 32, rows 16B-aligned
#define NCHUNK  180           // GK/8
#define GM2     10112         // 79*128: agg rows padded to GEMM M tiles
#define CAP     32            // fixed slots per node; overflow list handles the rest

typedef __bf16 bf16x8 __attribute__((ext_vector_type(8)));
typedef float  f32x4  __attribute__((ext_vector_type(4)));

typedef __attribute__((address_space(3))) unsigned int lds_u32;
typedef __attribute__((address_space(1))) unsigned int glb_u32;

__device__ __forceinline__ void stage16(const void* g, void* l) {
    __builtin_amdgcn_global_load_lds((glb_u32*)g, (lds_u32*)l, 16, 0, 0);
}

// ---------------- phase A: fill + conv + prep in ONE dispatch ----------------
// blocks [0, 196)          : edge binning -- ONE pass, no scan:
//                            pos = atomicAdd(&cnt[dst],1); pos<CAP -> slot,
//                            else overflow list (cnt[N_NODES] = ovf count).
// blocks [196, 2696)       : fp32->bf16 convert of X (4 rows/block)
// blocks [2696, 2786)      : W^T prep v2 -- COALESCED: f32x4 row reads ->
//                            16 KB LDS tile -> transposed bf16 writes.
//                            (v1 read W at stride 1024 B: 368 K scalar loads
//                            = ~23.6 MB of 64-B sectors for 1.5 MB payload,
//                            serialized at the phaseA tail.)
//
// conv window-select: wave w owns row r; row start mod 4 == r&3 == d
// (1433 % 4 == 1) -> uniform branch picks dwords [d..d+7] from 3 aligned
// float4 loads, ALL hoisted up front (one latency per row, not three).
// Loads clamp chunk to 178; chunk 178's 12-float window ends at col 1432
// (worst: row 9999, d=3 lands exactly on the last element 14,329,999).
// Chunk 179's single valid float (col 1432) sits at q[8+d] of that window.

#define FILL_BLKS   ((N_EDGES + 255) / 256)   // 196
#define CONV_BLKS   (N_NODES / 4)             // 2500
#define PREP_BLKS   (GK / 16)                 // 90: each block transposes 16 W-rows
#define PHASEA_BLKS (FILL_BLKS + CONV_BLKS + PREP_BLKS)

__global__ void __launch_bounds__(256) k_phaseA(const float* __restrict__ X,
                                                __bf16* __restrict__ Xbf,
                                                const float* __restrict__ W,
                                                __bf16* __restrict__ BT,
                                                const int* __restrict__ edges,
                                                int* __restrict__ cnt,
                                                int* __restrict__ slots,
                                                int* __restrict__ ovf) {
    __shared__ float wt[16][256];             // 16 KB (prep only; 10 blk/CU cap)
    const int t = threadIdx.x;
    const int b = blockIdx.x;

    if (b < FILL_BLKS) {
        // ---- edge binning: hist+fill collapsed into one atomic pass ----
        int e = b * 256 + t;
        if (e < N_EDGES) {
            int dst = edges[2 * e];
            int src = edges[2 * e + 1];
            if ((unsigned)src < N_NODES) {
                int pos = atomicAdd(&cnt[dst], 1);
                if (pos < CAP) {
                    slots[dst * CAP + pos] = src;
                } else {
                    int o = atomicAdd(&cnt[N_NODES], 1);
                    ovf[2 * o]     = dst;
                    ovf[2 * o + 1] = src;
                }
            }
        }
        return;
    }

    if (b < FILL_BLKS + CONV_BLKS) {
        // ---- conv: fp32 -> bf16, ILP-hoisted window-select ----
        const int w = t >> 6, lane = t & 63;
        const int r = (b - FILL_BLKS) * 4 + w;       // 0..9999
        const size_t rowf = (size_t)r * IN_F;
        __bf16* orow = Xbf + (size_t)r * GK;
        const int d = r & 3;

        f32x4 A[3][3];
#pragma unroll
        for (int s2 = 0; s2 < 3; ++s2) {
            int k = lane + s2 * 64;
            int kc = (k > 178) ? 178 : k;            // clamped: always in-bounds
            size_t q0 = (rowf + (size_t)kc * 8) >> 2;
            A[s2][0] = ((const f32x4*)X)[q0];
            A[s2][1] = ((const f32x4*)X)[q0 + 1];
            A[s2][2] = ((const f32x4*)X)[q0 + 2];
        }

#pragma unroll
        for (int s2 = 0; s2 < 3; ++s2) {
            int k = lane + s2 * 64;
            float q[12];
            *(f32x4*)&q[0] = A[s2][0];
            *(f32x4*)&q[4] = A[s2][1];
            *(f32x4*)&q[8] = A[s2][2];
            if (k < 179) {
                bf16x8 v;
                switch (d) {                          // wave-uniform
                case 0:
#pragma unroll
                    for (int j = 0; j < 8; ++j) v[j] = (__bf16)q[0 + j];
                    break;
                case 1:
#pragma unroll
                    for (int j = 0; j < 8; ++j) v[j] = (__bf16)q[1 + j];
                    break;
                case 2:
#pragma unroll
                    for (int j = 0; j < 8; ++j) v[j] = (__bf16)q[2 + j];
                    break;
                default:
#pragma unroll
                    for (int j = 0; j < 8; ++j) v[j] = (__bf16)q[3 + j];
                    break;
                }
                *(bf16x8*)(orow + k * 8) = v;
            } else if (k == 179) {
                bf16x8 v;
                v[0] = (__bf16)q[8 + d];              // float col 1432
#pragma unroll
                for (int j = 1; j < 8; ++j) v[j] = (__bf16)0.0f;
                *(bf16x8*)(orow + 1432) = v;
            }
        }
        return;
    }

    // ---- prep v2: coalesced W^T via LDS transpose; 16 W-rows per block ----
    {
        const int bp = b - FILL_BLKS - CONV_BLKS;     // 0..89
        const int k0 = bp * 16;
#pragma unroll
        for (int g2 = 0; g2 < 4; ++g2) {
            int g = t + g2 * 256;                     // f32x4 granule 0..1023
            int r = g >> 6, c4 = g & 63;              // row 0..15, col4 0..63
            int krow = k0 + r;
            f32x4 v = (krow < IN_F)
                        ? ((const f32x4*)(W + (size_t)krow * OUT_F))[c4]
                        : (f32x4){0.f, 0.f, 0.f, 0.f};  // zero-pad K 1433..1439
            *(f32x4*)&wt[r][c4 * 4] = v;
        }
        __syncthreads();
        bf16x8 o0, o1;                                // thread t = output col n
#pragma unroll
        for (int r = 0; r < 8; ++r) { o0[r] = (__bf16)wt[r][t]; o1[r] = (__bf16)wt[8 + r][t]; }
        *(bf16x8*)(BT + (size_t)t * GK + k0)     = o0;
        *(bf16x8*)(BT + (size_t)t * GK + k0 + 8) = o1;
    }
}

// ---------------- aggregate: slot-list gathers + fp32 noise init --------------
// agg[i] = noise[i] + sum_{src in N(i)} X[src];  rnorm[i] = 1/max(||agg||,1e-12)
// Neighbor list = slots[node*CAP .. node*CAP+min(cn,CAP)) plus (rare) overflow
// entries with dst==node. Slot reads are wave-uniform -> scalar broadcast.
// noise read DIRECTLY as fp32 with the window-select (d = node&3 block-uniform),
// loads issued before the gather loop so they fly under it.
// grid = GM2: pad rows just write zero (GEMM reads them).

__global__ void __launch_bounds__(192) k_agg(const __bf16* __restrict__ Xbf,
                                             const float* __restrict__ noise,
                                             const int* __restrict__ cnt,
                                             const int* __restrict__ slots,
                                             const int* __restrict__ ovf,
                                             __bf16* __restrict__ aggbf,
                                             float* __restrict__ rnorm) {
    __shared__ float red[3];
    const int node = blockIdx.x;
    const int t = threadIdx.x;
    const bool active = (t < NCHUNK);
    const size_t co = (size_t)t * 8;

    if (node >= N_NODES) {          // pad rows for the GEMM M-tiling
        if (active) {
            bf16x8 z;
#pragma unroll
            for (int j = 0; j < 8; ++j) z[j] = (__bf16)0.0f;
            *(bf16x8*)(aggbf + (size_t)node * GK + co) = z;
        }
        return;
    }

    const size_t nrowf = (size_t)node * IN_F;
    const int d = node & 3;
    f32x4 na, nb, nc;
    if (active) {
        int kc = (t > 178) ? 178 : t;
        size_t q0 = (nrowf + (size_t)kc * 8) >> 2;
        na = ((const f32x4*)noise)[q0];
        nb = ((const f32x4*)noise)[q0 + 1];
        nc = ((const f32x4*)noise)[q0 + 2];
    }

    const int cn = cnt[node];
    const int ns = (cn < CAP) ? cn : CAP;
    const int* sl = slots + node * CAP;

    float acc[8] = {0.f, 0.f, 0.f, 0.f, 0.f, 0.f, 0.f, 0.f};

    int kk = 0;
    for (; kk + 3 < ns; kk += 4) {
        int n0 = sl[kk], n1 = sl[kk + 1];
        int n2 = sl[kk + 2], n3 = sl[kk + 3];
        if (active) {
            bf16x8 v0 = *(const bf16x8*)(Xbf + (size_t)n0 * GK + co);
            bf16x8 v1 = *(const bf16x8*)(Xbf + (size_t)n1 * GK + co);
            bf16x8 v2 = *(const bf16x8*)(Xbf + (size_t)n2 * GK + co);
            bf16x8 v3 = *(const bf16x8*)(Xbf + (size_t)n3 * GK + co);
#pragma unroll
            for (int j = 0; j < 8; ++j)
                acc[j] += ((float)v0[j] + (float)v1[j]) + ((float)v2[j] + (float)v3[j]);
        }
    }
    for (; kk < ns; ++kk) {
        int n0 = sl[kk];
        if (active) {
            bf16x8 v = *(const bf16x8*)(Xbf + (size_t)n0 * GK + co);
#pragma unroll
            for (int j = 0; j < 8; ++j) acc[j] += (float)v[j];
        }
    }

    if (cn > CAP) {                  // exact overflow path (rare/never)
        const int L = cnt[N_NODES];
        for (int i = 0; i < L; ++i) {
            if (ovf[2 * i] == node) {
                int n0 = ovf[2 * i + 1];
                if (active) {
                    bf16x8 v = *(const bf16x8*)(Xbf + (size_t)n0 * GK + co);
#pragma unroll
                    for (int j = 0; j < 8; ++j) acc[j] += (float)v[j];
                }
            }
        }
    }

    // fold fp32 noise via window-select (block-uniform d)
    if (active) {
        float nq[12];
        *(f32x4*)&nq[0] = na; *(f32x4*)&nq[4] = nb; *(f32x4*)&nq[8] = nc;
        if (t < 179) {
            switch (d) {
            case 0:
#pragma unroll
                for (int j = 0; j < 8; ++j) acc[j] += nq[0 + j];
                break;
            case 1:
#pragma unroll
                for (int j = 0; j < 8; ++j) acc[j] += nq[1 + j];
                break;
            case 2:
#pragma unroll
                for (int j = 0; j < 8; ++j) acc[j] += nq[2 + j];
                break;
            default:
#pragma unroll
                for (int j = 0; j < 8; ++j) acc[j] += nq[3 + j];
                break;
            }
        } else {                      // t == 179: only float col 1432 is real
            acc[0] += nq[8 + d];
        }
    }

    float ss = 0.f;
    if (active) {
        bf16x8 o;
#pragma unroll
        for (int j = 0; j < 8; ++j) { o[j] = (__bf16)acc[j]; ss += acc[j] * acc[j]; }
        *(bf16x8*)(aggbf + (size_t)node * GK + co) = o;
    }
    for (int off = 32; off > 0; off >>= 1) ss += __shfl_down(ss, off, 64);
    if ((t & 63) == 0) red[t >> 6] = ss;
    __syncthreads();
    if (t == 0)
        rnorm[node] = 1.0f / fmaxf(sqrtf(red[0] + red[1] + red[2]), 1e-12f);
}

// ---------------- bf16 MFMA GEMM: out = (aggbf @ WbfT^T) * rnorm + bias --------
// v2: BM=64, BN=64, BK=96 -> 632 blocks (2.47/CU: better tail balance than
// 316@1.23), 15 K-iterations (30 barriers vs 90: each __syncthreads is a full
// vmcnt drain -- the dominant per-iter cost at this size). 4 waves in a 2x2
// grid, each 32x32 (2x2 of 16x16x32, K-accumulated over 3 sub-K).
// Frag reads stay bank-balanced: each instr covers 16 rows x 64 B at row
// stride 192 B -> 8 dwords/bank, structurally dense.
// XCD swizzle: 632 = 8*79 exactly (q=79, r=0) -> the 4 col-siblings sharing a
// 64-row A panel land consecutively on one XCD -> A re-reads are L2 hits.

#define BKG 96
#define GEMM_NWG ((GM2 / 64) * (OUT_F / 64))   // 158*4 = 632

__global__ void __launch_bounds__(256) k_gemm(const __bf16* __restrict__ A,
                                              const __bf16* __restrict__ BT,
                                              const float* __restrict__ rnorm,
                                              const float* __restrict__ bias,
                                              float* __restrict__ out) {
    __shared__ __align__(16) __bf16 Asm[64][BKG];   // 12 KB
    __shared__ __align__(16) __bf16 Bsm[64][BKG];   // 12 KB

    const int t = threadIdx.x;
    const int lane = t & 63;
    const int w = t >> 6;
    const int wr = w >> 1, wc = w & 1;              // 2x2 wave grid

    const int L = blockIdx.x;                        // XCD-bijective swizzle
    const int xcd = L & 7, idx = L >> 3;
    const int work = xcd * (GEMM_NWG / 8) + idx;     // 632 % 8 == 0
    const int row0 = (work >> 2) * 64;
    const int col0 = (work & 3) * 64;

    f32x4 acc[2][2];
#pragma unroll
    for (int i = 0; i < 2; ++i)
#pragma unroll
        for (int j = 0; j < 2; ++j) acc[i][j] = (f32x4){0.f, 0.f, 0.f, 0.f};

    __bf16* asm0 = (__bf16*)Asm;
    __bf16* bsm0 = (__bf16*)Bsm;

    // staging: 64 rows x 12 granules(16B) = 768 granules each side; 3/thread
    auto stage_tile = [&](int k0) {
#pragma unroll
        for (int g2 = 0; g2 < 3; ++g2) {
            int g = t + g2 * 256;
            int r = g / 12, c16 = g % 12;
            stage16(A  + (size_t)(row0 + r) * GK + k0 + c16 * 8, asm0 + g * 8);
            stage16(BT + (size_t)(col0 + r) * GK + k0 + c16 * 8, bsm0 + g * 8);
        }
    };

    stage_tile(0);

    const int kq = (lane >> 4) * 8;
    const int l15 = lane & 15;

    for (int kt = 0; kt < GK / BKG; ++kt) {
        __syncthreads();

        bf16x8 af[2][3], bfr[2][3];
#pragma unroll
        for (int s = 0; s < 3; ++s) {
#pragma unroll
            for (int i = 0; i < 2; ++i) {
                af[i][s]  = *(const bf16x8*)&Asm[wr * 32 + i * 16 + l15][s * 32 + kq];
                bfr[i][s] = *(const bf16x8*)&Bsm[wc * 32 + i * 16 + l15][s * 32 + kq];
            }
        }

        __syncthreads();

        if (kt + 1 < GK / BKG) stage_tile((kt + 1) * BKG);

#pragma unroll
        for (int s = 0; s < 3; ++s)
#pragma unroll
            for (int i = 0; i < 2; ++i)
#pragma unroll
                for (int j = 0; j < 2; ++j)
                    acc[i][j] = __builtin_amdgcn_mfma_f32_16x16x32_bf16(af[i][s], bfr[j][s], acc[i][j], 0, 0, 0);
    }

    // epilogue: C/D layout col=lane&15, row=(lane>>4)*4+reg; fuse rnorm + bias
    const int rq4 = (lane >> 4) * 4;
#pragma unroll
    for (int i = 0; i < 2; ++i) {
        int gr0 = row0 + wr * 32 + i * 16 + rq4;
#pragma unroll
        for (int rr = 0; rr < 4; ++rr) {
            int gr = gr0 + rr;
            if (gr < N_NODES) {
                float rn = rnorm[gr];
#pragma unroll
                for (int j = 0; j < 2; ++j) {
                    int gc = col0 + wc * 32 + j * 16 + l15;
                    out[(size_t)gr * OUT_F + gc] = acc[i][j][rr] * rn + bias[gc];
                }
            }
        }
    }
}

// ---------------- launch ----------------

extern "C" void kernel_launch(void* const* d_in, const int* in_sizes, int n_in,
                              void* d_out, int out_size, void* d_ws, size_t ws_size,
                              hipStream_t stream) {
    const float* feat  = (const float*)d_in[0];
    const int*   edges = (const int*)d_in[1];
    const float* W     = (const float*)d_in[2];
    const float* bias  = (const float*)d_in[3];
    const float* noise = (const float*)d_in[4];
    float* out = (float*)d_out;

    char* ws = (char*)d_ws;
    size_t off = 0;
    auto carve = [&](size_t bytes) {
        void* p = ws + off;
        off = (off + bytes + 255) & ~(size_t)255;
        return p;
    };
    __bf16* Xbf     = (__bf16*)carve((size_t)N_NODES * GK * sizeof(__bf16));
    __bf16* aggbf   = (__bf16*)carve((size_t)GM2 * GK * sizeof(__bf16));
    __bf16* WbfT    = (__bf16*)carve((size_t)OUT_F * GK * sizeof(__bf16));
    float*  rnorm   = (float*)carve((size_t)N_NODES * sizeof(float));
    int*    cnt     = (int*)carve((size_t)(N_NODES + 1) * sizeof(int));   // +ovf count
    int*    slots   = (int*)carve((size_t)N_NODES * CAP * sizeof(int));
    int*    ovf     = (int*)carve((size_t)2 * N_EDGES * sizeof(int));
    (void)ws_size;

    hipMemsetAsync(cnt, 0, (size_t)(N_NODES + 1) * sizeof(int), stream);

    k_phaseA<<<PHASEA_BLKS, 256, 0, stream>>>(feat, Xbf, W, WbfT,
                                              edges, cnt, slots, ovf);

    k_agg<<<GM2, 192, 0, stream>>>(Xbf, noise, cnt, slots, ovf, aggbf, rnorm);

    k_gemm<<<GEMM_NWG, 256, 0, stream>>>(aggbf, WbfT, rnorm, bias, out);
}